// Round 1
// baseline (323.868 us; speedup 1.0000x reference)
//
#include <hip/hip_runtime.h>

// Shapes: B=4, N=512, E=64; M = B*N = 2048.
// out[b,i,j,o] = sum_{d1,d2} x[b,i,d1] * y[b,j,d2] * Wc[o, d1*64+d2] + bc[o]
// Factored per block (4 mp rows = 4 (b,i) pairs):
//   U[mp][o][d2] = sum_{d1} x[mp][d1] * Wt[(o*64+d2)][d1]   (in-LDS, bf16)
//   out[mp][j][o] = sum_{d2} Y_b[j][d2] * U[mp][o][d2] + bc[o]
// U never touches HBM; output leaves via 1KB-contiguous dwordx4 NT stores.

typedef __bf16 bf16x8 __attribute__((ext_vector_type(8)));
typedef unsigned short u16x8 __attribute__((ext_vector_type(8)));
typedef float f32x16 __attribute__((ext_vector_type(16)));
typedef float f32x4  __attribute__((ext_vector_type(4)));

static __device__ inline unsigned short f2bf(float f) {
    unsigned int u = __float_as_uint(f);
    u = (u + 0x7FFFu + ((u >> 16) & 1u)) >> 16;   // RNE
    return (unsigned short)u;
}

static __device__ inline bf16x8 load_frag(const unsigned short* p) {
    u16x8 t = *(const u16x8*)p;     // 16B aligned by construction
    return __builtin_bit_cast(bf16x8, t);
}

// ---------------------------------------------------------------------------
// Kernel 1: fused LN+gate (blocks 0..511) and Wc transpose prep (512..575).
// ---------------------------------------------------------------------------
__global__ __launch_bounds__(256) void prep_kernel(
    const float* __restrict__ emb, const float* __restrict__ g,
    const float* __restrict__ bln,
    const float* __restrict__ W1, const float* __restrict__ b1,
    const float* __restrict__ W2, const float* __restrict__ b2,
    const float* __restrict__ Wc,
    unsigned short* __restrict__ xo, unsigned short* __restrict__ yo,
    unsigned short* __restrict__ wt)
{
    __shared__ __align__(16) float smem[64 * 65];
    const int bid = blockIdx.x;

    if (bid < 512) {
        // -------- LayerNorm + gated projections; one wave per row --------
        const int wave = threadIdx.x >> 6;
        const int lane = threadIdx.x & 63;
        const int row  = bid * 4 + wave;             // 0..2047

        float e = emb[row * 64 + lane];
        float s = e;
        #pragma unroll
        for (int m = 1; m < 64; m <<= 1) s += __shfl_xor(s, m);
        const float mu = s * (1.0f / 64.0f);
        const float d  = e - mu;
        float v = d * d;
        #pragma unroll
        for (int m = 1; m < 64; m <<= 1) v += __shfl_xor(v, m);
        const float rs = rsqrtf(v * (1.0f / 64.0f) + 1e-5f);
        const float h  = d * rs * g[lane] + bln[lane];

        float* hsh = smem + wave * 64;
        hsh[lane] = h;
        __syncthreads();

        const float4* hv  = (const float4*)hsh;
        const float4* w1v = (const float4*)(W1 + lane * 64);   // lane = o
        const float4* w2v = (const float4*)(W2 + lane * 64);
        float d1 = 0.f, d2 = 0.f;
        #pragma unroll
        for (int k = 0; k < 16; k++) {
            float4 hh = hv[k];
            float4 a  = w1v[k];
            float4 c  = w2v[k];
            d1 += hh.x * a.x + hh.y * a.y + hh.z * a.z + hh.w * a.w;
            d2 += hh.x * c.x + hh.y * c.y + hh.z * c.z + hh.w * c.w;
        }
        xo[row * 64 + lane] = f2bf(h * (d1 + b1[lane]));
        yo[row * 64 + lane] = f2bf(h * (d2 + b2[lane]));
    } else {
        // -------- Wc[o][d1*64+d2] (fp32) -> Wt[(o*64+d2)][d1] (bf16) --------
        float (*t)[65] = (float (*)[65])smem;
        const int o = bid - 512;                     // 0..63
        const float* src = Wc + o * 4096;
        for (int w = threadIdx.x; w < 4096; w += 256)
            t[w >> 6][w & 63] = src[w];              // t[d1][d2]
        __syncthreads();
        unsigned short* dst = wt + o * 4096;         // dst[d2*64 + d1]
        for (int w = threadIdx.x; w < 4096; w += 256) {
            int d2 = w >> 6, d1 = w & 63;
            dst[w] = f2bf(t[d1][d2]);
        }
    }
}

// ---------------------------------------------------------------------------
// Kernel 2: fused U-GEMM + output GEMM.
// Grid = 512 blocks (2/CU), 256 threads (4 waves). Block owns mp0..mp0+3.
// LDS: su = U tile [4][64][64] bf16, XOR-swizzled (32KB)
//      st = per-wave [32 j][64 o] fp32 transpose staging (4 x 8KB = 32KB)
// Stage 1: U = X(4x64) @ Wt^T via 32x32x16 MFMA (rows 4..31 zeroed).
// Stage 2: per (j-tile, mp): acc = Y @ U^T, +bias, LDS transpose,
//          8 x dwordx4 NT stores of 1KB fully-contiguous each.
// ---------------------------------------------------------------------------
__global__ __launch_bounds__(256) void uo_kernel(
    const unsigned short* __restrict__ x, const unsigned short* __restrict__ y,
    const unsigned short* __restrict__ wt, const float* __restrict__ bc,
    float* __restrict__ out)
{
    __shared__ __align__(16) unsigned short su[4 * 4096];   // 32 KB
    __shared__ __align__(16) float st[4][32 * 64];          // 32 KB

    const int wave = threadIdx.x >> 6;
    const int lane = threadIdx.x & 63;
    const int lr = lane & 31, lh = lane >> 5;
    const int mp0 = blockIdx.x * 4;                 // 0..2044
    const int b   = mp0 >> 9;                       // N = 512

    // ---------------- Stage 1: U tile into LDS ----------------
    const u16x8 zz = {};
    bf16x8 xa[4];
    #pragma unroll
    for (int ks = 0; ks < 4; ks++) {
        xa[ks] = (lr < 4)
            ? load_frag(x + (mp0 + lr) * 64 + ks * 16 + lh * 8)
            : __builtin_bit_cast(bf16x8, zz);
    }

    // each wave covers 32 n-tiles of 32 cols (n = o*64 + d2)
    for (int i = 0; i < 32; i++) {
        const int n0 = (wave * 32 + i) * 32;
        bf16x8 bfr[4];
        #pragma unroll
        for (int ks = 0; ks < 4; ks++)
            bfr[ks] = load_frag(wt + (n0 + lr) * 64 + ks * 16 + lh * 8);
        f32x16 acc = {};
        #pragma unroll
        for (int ks = 0; ks < 4; ks++)
            acc = __builtin_amdgcn_mfma_f32_32x32x16_bf16(xa[ks], bfr[ks], acc, 0, 0, 0);
        if (lh == 0) {
            // rows 0..3 (= mp) live in lanes 0..31, regs r=0..3
            const int o  = n0 >> 6;                  // uniform over the tile
            const int d2 = (n0 & 63) + lr;
            const int sw = (o & 7) << 3;             // XOR swizzle, 16B granular
            #pragma unroll
            for (int r = 0; r < 4; r++)
                su[(r * 4096 + o * 64 + d2) ^ sw] = f2bf(acc[r]);
        }
    }
    __syncthreads();

    // ---------------- Stage 2: out = Y_b @ U^T + bc ----------------
    const float bias0 = bc[lr];
    const float bias1 = bc[32 + lr];
    const unsigned short* yb = y + b * (512 * 64);
    float* st_w = st[wave];
    const int swz = (lr & 7) << 3;                   // (o&7) identical for o=lr, 32+lr

    for (int jt = 0; jt < 4; jt++) {
        const int j0 = wave * 128 + jt * 32;
        bf16x8 af[4];
        #pragma unroll
        for (int ks = 0; ks < 4; ks++)
            af[ks] = load_frag(yb + (j0 + lr) * 64 + ks * 16 + lh * 8);

        #pragma unroll
        for (int mp = 0; mp < 4; mp++) {
            f32x16 acc0 = {}, acc1 = {};
            #pragma unroll
            for (int ks = 0; ks < 4; ks++) {
                const int kofs = ks * 16 + lh * 8;
                bf16x8 b0 = load_frag(&su[(mp * 4096 + lr * 64        + kofs) ^ swz]);
                bf16x8 b1 = load_frag(&su[(mp * 4096 + (32 + lr) * 64 + kofs) ^ swz]);
                acc0 = __builtin_amdgcn_mfma_f32_32x32x16_bf16(af[ks], b0, acc0, 0, 0, 0);
                acc1 = __builtin_amdgcn_mfma_f32_32x32x16_bf16(af[ks], b1, acc1, 0, 0, 0);
            }
            // transpose via wave-private LDS: st_w[j_local][o]
            #pragma unroll
            for (int r = 0; r < 16; r++) {
                const int jl = (r & 3) + 8 * (r >> 2) + 4 * lh;   // 0..31
                st_w[jl * 64 + lr]      = acc0[r] + bias0;
                st_w[jl * 64 + 32 + lr] = acc1[r] + bias1;
            }
            // 1KB-contiguous NT stores: lane t writes st_w[q*256 + t*4 .. +3]
            float* outp = out + (size_t)(mp0 + mp) * 32768 + j0 * 64;
            #pragma unroll
            for (int q = 0; q < 8; q++) {
                f32x4 v = *(const f32x4*)&st_w[q * 256 + lane * 4];
                __builtin_nontemporal_store(v, (f32x4*)(outp + q * 256 + lane * 4));
            }
        }
    }
}

// ---------------------------------------------------------------------------
extern "C" void kernel_launch(void* const* d_in, const int* in_sizes, int n_in,
                              void* d_out, int out_size, void* d_ws, size_t ws_size,
                              hipStream_t stream) {
    const float* emb  = (const float*)d_in[0];
    // d_in[1] = node_mask (unused by forward)
    const float* ln_g = (const float*)d_in[2];
    const float* ln_b = (const float*)d_in[3];
    const float* W1   = (const float*)d_in[4];
    const float* b1   = (const float*)d_in[5];
    const float* W2   = (const float*)d_in[6];
    const float* b2   = (const float*)d_in[7];
    const float* Wc   = (const float*)d_in[8];
    const float* bc   = (const float*)d_in[9];
    float* out = (float*)d_out;

    char* ws = (char*)d_ws;
    unsigned short* x_ws  = (unsigned short*)(ws);              // 2048*64*2  = 256 KB
    unsigned short* y_ws  = (unsigned short*)(ws + 262144);     // 256 KB
    unsigned short* wt_ws = (unsigned short*)(ws + 524288);     // 4096*64*2  = 512 KB

    hipLaunchKernelGGL(prep_kernel, dim3(576), dim3(256), 0, stream,
                       emb, ln_g, ln_b, W1, b1, W2, b2, Wc, x_ws, y_ws, wt_ws);
    hipLaunchKernelGGL(uo_kernel, dim3(512), dim3(256), 0, stream,
                       x_ws, y_ws, wt_ws, bc, out);
}

// Round 4
// 311.603 us; speedup vs baseline: 1.0394x; 1.0394x over previous
//
#include <hip/hip_runtime.h>

// Shapes: B=4, N=512, E=64; M = B*N = 2048.
// out[b,i,j,o] = sum_{d1,d2} x[b,i,d1] * y[b,j,d2] * Wc[o, d1*64+d2] + bc[o]
// Factored per block (4 mp rows = 4 (b,i) pairs):
//   U[mp][o][d2] = sum_{d1} x[mp][d1] * Wt[(o*64+d2)][d1]   (in-LDS, bf16)
//   out[mp][j][o] = sum_{d2} Y_b[j][d2] * U[mp][o][d2] + bc[o]
// R2 A/B (3rd submit): identical to R1 except output stores are PLAIN (L2
// writeback), not nontemporal — testing "nt caps streaming writes ~1.9 TB/s".

typedef __bf16 bf16x8 __attribute__((ext_vector_type(8)));
typedef unsigned short u16x8 __attribute__((ext_vector_type(8)));
typedef float f32x16 __attribute__((ext_vector_type(16)));
typedef float f32x4  __attribute__((ext_vector_type(4)));

static __device__ inline unsigned short f2bf(float f) {
    unsigned int u = __float_as_uint(f);
    u = (u + 0x7FFFu + ((u >> 16) & 1u)) >> 16;   // RNE
    return (unsigned short)u;
}

static __device__ inline bf16x8 load_frag(const unsigned short* p) {
    u16x8 t = *(const u16x8*)p;     // 16B aligned by construction
    return __builtin_bit_cast(bf16x8, t);
}

// ---------------------------------------------------------------------------
// Kernel 1: fused LN+gate (blocks 0..511) and Wc transpose prep (512..575).
// ---------------------------------------------------------------------------
__global__ __launch_bounds__(256) void prep_kernel(
    const float* __restrict__ emb, const float* __restrict__ g,
    const float* __restrict__ bln,
    const float* __restrict__ W1, const float* __restrict__ b1,
    const float* __restrict__ W2, const float* __restrict__ b2,
    const float* __restrict__ Wc,
    unsigned short* __restrict__ xo, unsigned short* __restrict__ yo,
    unsigned short* __restrict__ wt)
{
    __shared__ __align__(16) float smem[64 * 65];
    const int bid = blockIdx.x;

    if (bid < 512) {
        // -------- LayerNorm + gated projections; one wave per row --------
        const int wave = threadIdx.x >> 6;
        const int lane = threadIdx.x & 63;
        const int row  = bid * 4 + wave;             // 0..2047

        float e = emb[row * 64 + lane];
        float s = e;
        #pragma unroll
        for (int m = 1; m < 64; m <<= 1) s += __shfl_xor(s, m);
        const float mu = s * (1.0f / 64.0f);
        const float d  = e - mu;
        float v = d * d;
        #pragma unroll
        for (int m = 1; m < 64; m <<= 1) v += __shfl_xor(v, m);
        const float rs = rsqrtf(v * (1.0f / 64.0f) + 1e-5f);
        const float h  = d * rs * g[lane] + bln[lane];

        float* hsh = smem + wave * 64;
        hsh[lane] = h;
        __syncthreads();

        const float4* hv  = (const float4*)hsh;
        const float4* w1v = (const float4*)(W1 + lane * 64);   // lane = o
        const float4* w2v = (const float4*)(W2 + lane * 64);
        float d1 = 0.f, d2 = 0.f;
        #pragma unroll
        for (int k = 0; k < 16; k++) {
            float4 hh = hv[k];
            float4 a  = w1v[k];
            float4 c  = w2v[k];
            d1 += hh.x * a.x + hh.y * a.y + hh.z * a.z + hh.w * a.w;
            d2 += hh.x * c.x + hh.y * c.y + hh.z * c.z + hh.w * c.w;
        }
        xo[row * 64 + lane] = f2bf(h * (d1 + b1[lane]));
        yo[row * 64 + lane] = f2bf(h * (d2 + b2[lane]));
    } else {
        // -------- Wc[o][d1*64+d2] (fp32) -> Wt[(o*64+d2)][d1] (bf16) --------
        float (*t)[65] = (float (*)[65])smem;
        const int o = bid - 512;                     // 0..63
        const float* src = Wc + o * 4096;
        for (int w = threadIdx.x; w < 4096; w += 256)
            t[w >> 6][w & 63] = src[w];              // t[d1][d2]
        __syncthreads();
        unsigned short* dst = wt + o * 4096;         // dst[d2*64 + d1]
        for (int w = threadIdx.x; w < 4096; w += 256) {
            int d2 = w >> 6, d1 = w & 63;
            dst[w] = f2bf(t[d1][d2]);
        }
    }
}

// ---------------------------------------------------------------------------
// Kernel 2: fused U-GEMM + output GEMM.
// Grid = 512 blocks (2/CU), 256 threads (4 waves). Block owns mp0..mp0+3.
// LDS: su = U tile [4][64][64] bf16, XOR-swizzled (32KB)
//      st = per-wave [32 j][64 o] fp32 transpose staging (4 x 8KB = 32KB)
// Stage 1: U = X(4x64) @ Wt^T via 32x32x16 MFMA (rows 4..31 zeroed).
// Stage 2: per (j-tile, mp): acc = Y @ U^T, +bias, LDS transpose,
//          8 x dwordx4 PLAIN stores of 1KB fully-contiguous each.
// ---------------------------------------------------------------------------
__global__ __launch_bounds__(256) void uo_kernel(
    const unsigned short* __restrict__ x, const unsigned short* __restrict__ y,
    const unsigned short* __restrict__ wt, const float* __restrict__ bc,
    float* __restrict__ out)
{
    __shared__ __align__(16) unsigned short su[4 * 4096];   // 32 KB
    __shared__ __align__(16) float st[4][32 * 64];          // 32 KB

    const int wave = threadIdx.x >> 6;
    const int lane = threadIdx.x & 63;
    const int lr = lane & 31, lh = lane >> 5;
    const int mp0 = blockIdx.x * 4;                 // 0..2044
    const int b   = mp0 >> 9;                       // N = 512

    // ---------------- Stage 1: U tile into LDS ----------------
    const u16x8 zz = {};
    bf16x8 xa[4];
    #pragma unroll
    for (int ks = 0; ks < 4; ks++) {
        xa[ks] = (lr < 4)
            ? load_frag(x + (mp0 + lr) * 64 + ks * 16 + lh * 8)
            : __builtin_bit_cast(bf16x8, zz);
    }

    // each wave covers 32 n-tiles of 32 cols (n = o*64 + d2)
    for (int i = 0; i < 32; i++) {
        const int n0 = (wave * 32 + i) * 32;
        bf16x8 bfr[4];
        #pragma unroll
        for (int ks = 0; ks < 4; ks++)
            bfr[ks] = load_frag(wt + (n0 + lr) * 64 + ks * 16 + lh * 8);
        f32x16 acc = {};
        #pragma unroll
        for (int ks = 0; ks < 4; ks++)
            acc = __builtin_amdgcn_mfma_f32_32x32x16_bf16(xa[ks], bfr[ks], acc, 0, 0, 0);
        if (lh == 0) {
            // rows 0..3 (= mp) live in lanes 0..31, regs r=0..3
            const int o  = n0 >> 6;                  // uniform over the tile
            const int d2 = (n0 & 63) + lr;
            const int sw = (o & 7) << 3;             // XOR swizzle, 16B granular
            #pragma unroll
            for (int r = 0; r < 4; r++)
                su[(r * 4096 + o * 64 + d2) ^ sw] = f2bf(acc[r]);
        }
    }
    __syncthreads();

    // ---------------- Stage 2: out = Y_b @ U^T + bc ----------------
    const float bias0 = bc[lr];
    const float bias1 = bc[32 + lr];
    const unsigned short* yb = y + b * (512 * 64);
    float* st_w = st[wave];
    const int swz = (lr & 7) << 3;                   // (o&7) identical for o=lr, 32+lr

    for (int jt = 0; jt < 4; jt++) {
        const int j0 = wave * 128 + jt * 32;
        bf16x8 af[4];
        #pragma unroll
        for (int ks = 0; ks < 4; ks++)
            af[ks] = load_frag(yb + (j0 + lr) * 64 + ks * 16 + lh * 8);

        #pragma unroll
        for (int mp = 0; mp < 4; mp++) {
            f32x16 acc0 = {}, acc1 = {};
            #pragma unroll
            for (int ks = 0; ks < 4; ks++) {
                const int kofs = ks * 16 + lh * 8;
                bf16x8 b0 = load_frag(&su[(mp * 4096 + lr * 64        + kofs) ^ swz]);
                bf16x8 b1 = load_frag(&su[(mp * 4096 + (32 + lr) * 64 + kofs) ^ swz]);
                acc0 = __builtin_amdgcn_mfma_f32_32x32x16_bf16(af[ks], b0, acc0, 0, 0, 0);
                acc1 = __builtin_amdgcn_mfma_f32_32x32x16_bf16(af[ks], b1, acc1, 0, 0, 0);
            }
            // transpose via wave-private LDS: st_w[j_local][o]
            #pragma unroll
            for (int r = 0; r < 16; r++) {
                const int jl = (r & 3) + 8 * (r >> 2) + 4 * lh;   // 0..31
                st_w[jl * 64 + lr]      = acc0[r] + bias0;
                st_w[jl * 64 + 32 + lr] = acc1[r] + bias1;
            }
            // 1KB-contiguous PLAIN stores: lane t writes st_w[q*256 + t*4 .. +3]
            float* outp = out + (size_t)(mp0 + mp) * 32768 + j0 * 64;
            #pragma unroll
            for (int q = 0; q < 8; q++) {
                f32x4 v = *(const f32x4*)&st_w[q * 256 + lane * 4];
                *(f32x4*)(outp + q * 256 + lane * 4) = v;
            }
        }
    }
}

// ---------------------------------------------------------------------------
extern "C" void kernel_launch(void* const* d_in, const int* in_sizes, int n_in,
                              void* d_out, int out_size, void* d_ws, size_t ws_size,
                              hipStream_t stream) {
    const float* emb  = (const float*)d_in[0];
    // d_in[1] = node_mask (unused by forward)
    const float* ln_g = (const float*)d_in[2];
    const float* ln_b = (const float*)d_in[3];
    const float* W1   = (const float*)d_in[4];
    const float* b1   = (const float*)d_in[5];
    const float* W2   = (const float*)d_in[6];
    const float* b2   = (const float*)d_in[7];
    const float* Wc   = (const float*)d_in[8];
    const float* bc   = (const float*)d_in[9];
    float* out = (float*)d_out;

    char* ws = (char*)d_ws;
    unsigned short* x_ws  = (unsigned short*)(ws);              // 2048*64*2  = 256 KB
    unsigned short* y_ws  = (unsigned short*)(ws + 262144);     // 256 KB
    unsigned short* wt_ws = (unsigned short*)(ws + 524288);     // 4096*64*2  = 512 KB

    hipLaunchKernelGGL(prep_kernel, dim3(576), dim3(256), 0, stream,
                       emb, ln_g, ln_b, W1, b1, W2, b2, Wc, x_ws, y_ws, wt_ws);
    hipLaunchKernelGGL(uo_kernel, dim3(512), dim3(256), 0, stream,
                       x_ws, y_ws, wt_ws, bc, out);
}